// Round 12
// baseline (349.349 us; speedup 1.0000x reference)
//
#include <hip/hip_runtime.h>

#define N_NODES 100000
#define N_EDGES 1600000
#define IN_DIM 64
#define HID 128
#define N_GRAPHS 512
#define NBUCK 391    // ceil(100000/256) buckets of 256 nodes

// ---------------- pass A: per-block LDS histogram of src/dst buckets ----------------
__global__ __launch_bounds__(256) void k_bhist(const int* __restrict__ src, const int* __restrict__ dst,
                                               int* __restrict__ dcnt, int* __restrict__ scnt) {
    __shared__ int hd[NBUCK];
    __shared__ int hs[NBUCK];
    const int t = threadIdx.x;
    const int e0 = blockIdx.x * 4096 + t * 16;
    for (int i = t; i < NBUCK; i += 256) { hd[i] = 0; hs[i] = 0; }
    __syncthreads();
    if (e0 < N_EDGES) {
        const int4* d4 = (const int4*)(dst + e0);
        const int4* s4 = (const int4*)(src + e0);
#pragma unroll
        for (int u = 0; u < 4; ++u) {
            int4 d = d4[u], s = s4[u];
            atomicAdd(&hd[d.x >> 8], 1); atomicAdd(&hd[d.y >> 8], 1);
            atomicAdd(&hd[d.z >> 8], 1); atomicAdd(&hd[d.w >> 8], 1);
            atomicAdd(&hs[s.x >> 8], 1); atomicAdd(&hs[s.y >> 8], 1);
            atomicAdd(&hs[s.z >> 8], 1); atomicAdd(&hs[s.w >> 8], 1);
        }
    }
    __syncthreads();
    for (int i = t; i < NBUCK; i += 256) {
        if (hd[i]) atomicAdd(&dcnt[i], hd[i]);
        if (hs[i]) atomicAdd(&scnt[i], hs[i]);
    }
}

// ---------------- scans (blocks 0,1) + per-graph bounds (block 2) ----------------
__global__ __launch_bounds__(512) void k_bscan3(const int* __restrict__ dcnt, const int* __restrict__ scnt,
                                                const int* __restrict__ gid,
                                                int* __restrict__ dbase, int* __restrict__ sbase,
                                                int* __restrict__ dcur, int* __restrict__ scur,
                                                int* __restrict__ gstart) {
    const int t = threadIdx.x;
    if (blockIdx.x == 2) {
        for (int g = t; g <= N_GRAPHS; g += 512) {
            int lo = 0, hi = N_NODES;
            while (lo < hi) {
                int mid = (lo + hi) >> 1;
                if (gid[mid] < g) lo = mid + 1; else hi = mid;
            }
            gstart[g] = lo;
        }
        return;
    }
    __shared__ int l[512];
    const int* cntp = (blockIdx.x == 0) ? dcnt : scnt;
    int* basep = (blockIdx.x == 0) ? dbase : sbase;
    int* curp  = (blockIdx.x == 0) ? dcur  : scur;
    int v = (t < NBUCK) ? cntp[t] : 0;
    l[t] = v;
    __syncthreads();
    for (int off = 1; off < 512; off <<= 1) {
        int x = (t >= off) ? l[t - off] : 0;
        __syncthreads();
        l[t] += x;
        __syncthreads();
    }
    if (t < NBUCK) {
        int excl = l[t] - v;
        basep[t] = excl; curp[t] = excl;
    }
    if (t == NBUCK - 1) basep[NBUCK] = l[t];
}

// ---------------- pass B: bin by dst bucket (packed src|dstLocal) AND by src bucket ----------------
__global__ __launch_bounds__(256) void k_bin2(const int* __restrict__ src, const int* __restrict__ dst,
                                              int* __restrict__ dcur, int* __restrict__ scur,
                                              int* __restrict__ binnedD, int* __restrict__ binnedS) {
    __shared__ int hd[NBUCK];
    __shared__ int bd[NBUCK];
    __shared__ int hs[NBUCK];
    __shared__ int bs[NBUCK];
    const int t = threadIdx.x;
    const int e0 = blockIdx.x * 4096 + t * 16;
    for (int i = t; i < NBUCK; i += 256) { hd[i] = 0; hs[i] = 0; }
    __syncthreads();
    if (e0 < N_EDGES) {
        const int4* d4 = (const int4*)(dst + e0);
        const int4* s4 = (const int4*)(src + e0);
#pragma unroll
        for (int u = 0; u < 4; ++u) {
            int4 d = d4[u], s = s4[u];
            atomicAdd(&hd[d.x >> 8], 1); atomicAdd(&hd[d.y >> 8], 1);
            atomicAdd(&hd[d.z >> 8], 1); atomicAdd(&hd[d.w >> 8], 1);
            atomicAdd(&hs[s.x >> 8], 1); atomicAdd(&hs[s.y >> 8], 1);
            atomicAdd(&hs[s.z >> 8], 1); atomicAdd(&hs[s.w >> 8], 1);
        }
    }
    __syncthreads();
    for (int i = t; i < NBUCK; i += 256) {
        int c = hd[i];
        bd[i] = c ? atomicAdd(&dcur[i], c) : 0;
        hd[i] = 0;
        c = hs[i];
        bs[i] = c ? atomicAdd(&scur[i], c) : 0;
        hs[i] = 0;
    }
    __syncthreads();
    if (e0 < N_EDGES) {
        const int4* d4 = (const int4*)(dst + e0);
        const int4* s4 = (const int4*)(src + e0);
#pragma unroll
        for (int u = 0; u < 4; ++u) {
            int4 d = d4[u];
            int4 s = s4[u];
            int bk, r;
            bk = d.x >> 8; r = atomicAdd(&hd[bk], 1); binnedD[bd[bk] + r] = s.x | ((d.x & 255) << 17);
            bk = d.y >> 8; r = atomicAdd(&hd[bk], 1); binnedD[bd[bk] + r] = s.y | ((d.y & 255) << 17);
            bk = d.z >> 8; r = atomicAdd(&hd[bk], 1); binnedD[bd[bk] + r] = s.z | ((d.z & 255) << 17);
            bk = d.w >> 8; r = atomicAdd(&hd[bk], 1); binnedD[bd[bk] + r] = s.w | ((d.w & 255) << 17);
            bk = s.x >> 8; r = atomicAdd(&hs[bk], 1); binnedS[bs[bk] + r] = s.x;
            bk = s.y >> 8; r = atomicAdd(&hs[bk], 1); binnedS[bs[bk] + r] = s.y;
            bk = s.z >> 8; r = atomicAdd(&hs[bk], 1); binnedS[bs[bk] + r] = s.z;
            bk = s.w >> 8; r = atomicAdd(&hs[bk], 1); binnedS[bs[bk] + r] = s.w;
        }
    }
}

// ---------------- pass C: CSR build (blocks 0..NBUCK-1) + out-degree rso (blocks NBUCK..) ----------------
__global__ __launch_bounds__(256) void k_prep2(const int* __restrict__ dbase, const int* __restrict__ sbase,
                                               const int* __restrict__ binnedD, const int* __restrict__ binnedS,
                                               int* __restrict__ rowp, float* __restrict__ rsi,
                                               float* __restrict__ rso, int* __restrict__ col) {
    const int t = threadIdx.x;
    if (blockIdx.x < NBUCK) {
        const int b = blockIdx.x;
        const int n0 = b * 256;
        __shared__ int cnt[256];
        __shared__ int scn[256];
        __shared__ int cur[256];
        __shared__ int sb[2];
        if (t < 2) sb[t] = dbase[b + t];
        cnt[t] = 0;
        __syncthreads();
        const int s = sb[0], e = sb[1];
        for (int i = s + t; i < e; i += 256) atomicAdd(&cnt[binnedD[i] >> 17], 1);
        __syncthreads();
        const int c = cnt[t];
        scn[t] = c;
        __syncthreads();
        for (int off = 1; off < 256; off <<= 1) {
            int v = (t >= off) ? scn[t - off] : 0;
            __syncthreads();
            scn[t] += v;
            __syncthreads();
        }
        const int excl = scn[t] - c;
        cur[t] = excl;
        if (n0 + t < N_NODES) {
            rowp[n0 + t] = s + excl;
            rsi[n0 + t] = 1.0f / sqrtf(fmaxf((float)c, 1.0f));
        }
        if (b == NBUCK - 1 && t == 0) rowp[N_NODES] = e;
        __syncthreads();
        for (int i = s + t; i < e; i += 256) {
            int p = binnedD[i];
            int r = atomicAdd(&cur[p >> 17], 1);
            col[s + r] = p & 0x1FFFF;
        }
    } else {
        const int b = blockIdx.x - NBUCK;
        const int n0 = b * 256;
        __shared__ int cnt2[256];
        __shared__ int sb2[2];
        if (t < 2) sb2[t] = sbase[b + t];
        cnt2[t] = 0;
        __syncthreads();
        const int s = sb2[0], e = sb2[1];
        for (int i = s + t; i < e; i += 256) atomicAdd(&cnt2[binnedS[i] - n0], 1);
        __syncthreads();
        if (n0 + t < N_NODES) rso[n0 + t] = 1.0f / sqrtf(fmaxf((float)cnt2[t], 1.0f));
    }
}

// ---------------- fused layer-1: gather(64) -> LDS -> matmul W1 (LDS-staged) -> h1s ----------------
__global__ __launch_bounds__(512, 8) void k_g64mm(const float4* __restrict__ x4, const float* __restrict__ rso,
                                                  const int* __restrict__ rowp, const int* __restrict__ col,
                                                  const float* __restrict__ W, const float* __restrict__ bias,
                                                  const float* __restrict__ rsi, float* __restrict__ out) {
    __shared__ float aggL[32][IN_DIM];   // 8 KB
    __shared__ float WL[32 * 128];       // 16 KB
    const int t = threadIdx.x;
    const int wid = t >> 6, lane = t & 63;
    const int n0 = blockIdx.x * 32;

    const int grp = lane >> 4, li = lane & 15;
#pragma unroll 1
    for (int it = 0; it < 4; ++it) {
        const int node = n0 + wid * 4 + it;
        const int s = rowp[node], e = rowp[node + 1];
        float ax = 0.f, ay = 0.f, az = 0.f, aw = 0.f;
        int i = s + grp;
        for (; i + 12 < e; i += 16) {
            int c0 = col[i], c1 = col[i + 4], c2 = col[i + 8], c3 = col[i + 12];
            float4 v0 = x4[c0 * 16 + li];
            float4 v1 = x4[c1 * 16 + li];
            float4 v2 = x4[c2 * 16 + li];
            float4 v3 = x4[c3 * 16 + li];
            float r0 = rso[c0], r1 = rso[c1], r2 = rso[c2], r3 = rso[c3];
            ax = fmaf(r0, v0.x, ax); ay = fmaf(r0, v0.y, ay); az = fmaf(r0, v0.z, az); aw = fmaf(r0, v0.w, aw);
            ax = fmaf(r1, v1.x, ax); ay = fmaf(r1, v1.y, ay); az = fmaf(r1, v1.z, az); aw = fmaf(r1, v1.w, aw);
            ax = fmaf(r2, v2.x, ax); ay = fmaf(r2, v2.y, ay); az = fmaf(r2, v2.z, az); aw = fmaf(r2, v2.w, aw);
            ax = fmaf(r3, v3.x, ax); ay = fmaf(r3, v3.y, ay); az = fmaf(r3, v3.z, az); aw = fmaf(r3, v3.w, aw);
        }
        for (; i + 4 < e; i += 8) {
            int c0 = col[i], c1 = col[i + 4];
            float4 v0 = x4[c0 * 16 + li];
            float4 v1 = x4[c1 * 16 + li];
            float r0 = rso[c0], r1 = rso[c1];
            ax = fmaf(r0, v0.x, ax); ay = fmaf(r0, v0.y, ay); az = fmaf(r0, v0.z, az); aw = fmaf(r0, v0.w, aw);
            ax = fmaf(r1, v1.x, ax); ay = fmaf(r1, v1.y, ay); az = fmaf(r1, v1.z, az); aw = fmaf(r1, v1.w, aw);
        }
        for (; i < e; i += 4) {
            int c = col[i];
            float4 v = x4[c * 16 + li];
            float r = rso[c];
            ax = fmaf(r, v.x, ax); ay = fmaf(r, v.y, ay); az = fmaf(r, v.z, az); aw = fmaf(r, v.w, aw);
        }
        ax += __shfl_xor(ax, 16, 64); ay += __shfl_xor(ay, 16, 64);
        az += __shfl_xor(az, 16, 64); aw += __shfl_xor(aw, 16, 64);
        ax += __shfl_xor(ax, 32, 64); ay += __shfl_xor(ay, 32, 64);
        az += __shfl_xor(az, 32, 64); aw += __shfl_xor(aw, 32, 64);
        if (lane < 16) {
            float4 o; o.x = ax; o.y = ay; o.z = az; o.w = aw;
            ((float4*)aggL[node - n0])[li] = o;
        }
    }

    const int jq = t & 31;
    const int ns = t >> 5;
    float acc[2][4] = {};
    for (int kc = 0; kc < IN_DIM; kc += 32) {
        const float4* Wg = (const float4*)(W + kc * 128);
        float4* WL4 = (float4*)WL;
        __syncthreads();
#pragma unroll
        for (int u = 0; u < 2; ++u) WL4[t + 512 * u] = Wg[t + 512 * u];
        __syncthreads();
#pragma unroll
        for (int k = 0; k < 32; ++k) {
            float4 wv = ((const float4*)WL)[k * 32 + jq];
            float a0 = aggL[ns * 2 + 0][kc + k];
            float a1 = aggL[ns * 2 + 1][kc + k];
            acc[0][0] += a0 * wv.x; acc[0][1] += a0 * wv.y; acc[0][2] += a0 * wv.z; acc[0][3] += a0 * wv.w;
            acc[1][0] += a1 * wv.x; acc[1][1] += a1 * wv.y; acc[1][2] += a1 * wv.z; acc[1][3] += a1 * wv.w;
        }
    }
    float4 bj = ((const float4*)bias)[jq];
#pragma unroll
    for (int i = 0; i < 2; ++i) {
        int node = n0 + ns * 2 + i;
        float ri = rsi[node];
        float ro = rso[node];
        float4 o;
        o.x = fmaxf(acc[i][0] * ri + bj.x, 0.f) * ro;
        o.y = fmaxf(acc[i][1] * ri + bj.y, 0.f) * ro;
        o.z = fmaxf(acc[i][2] * ri + bj.z, 0.f) * ro;
        o.w = fmaxf(acc[i][3] * ri + bj.w, 0.f) * ro;
        *(float4*)(out + (size_t)node * HID + jq * 4) = o;
    }
}

// ---------------- standalone gather (128-dim): one wave per node, 8-unroll ----------------
__global__ __launch_bounds__(256) void k_gather128(const float4* __restrict__ h4, const int* __restrict__ rowp,
                                                   const int* __restrict__ col, float4* __restrict__ agg4) {
    int wv = (blockIdx.x * 256 + threadIdx.x) >> 6;
    if (wv >= N_NODES) return;
    int lane = threadIdx.x & 63;
    int grp = lane >> 5, li = lane & 31;
    int s = rowp[wv], e = rowp[wv + 1];
    float ax = 0.f, ay = 0.f, az = 0.f, aw = 0.f;
    int i = s + grp;
    for (; i + 14 < e; i += 16) {
        int c0 = col[i],      c1 = col[i + 2],  c2 = col[i + 4],  c3 = col[i + 6];
        int c4 = col[i + 8],  c5 = col[i + 10], c6 = col[i + 12], c7 = col[i + 14];
        float4 v0 = h4[c0 * 32 + li];
        float4 v1 = h4[c1 * 32 + li];
        float4 v2 = h4[c2 * 32 + li];
        float4 v3 = h4[c3 * 32 + li];
        float4 v4 = h4[c4 * 32 + li];
        float4 v5 = h4[c5 * 32 + li];
        float4 v6 = h4[c6 * 32 + li];
        float4 v7 = h4[c7 * 32 + li];
        ax += (v0.x + v1.x) + (v2.x + v3.x) + ((v4.x + v5.x) + (v6.x + v7.x));
        ay += (v0.y + v1.y) + (v2.y + v3.y) + ((v4.y + v5.y) + (v6.y + v7.y));
        az += (v0.z + v1.z) + (v2.z + v3.z) + ((v4.z + v5.z) + (v6.z + v7.z));
        aw += (v0.w + v1.w) + (v2.w + v3.w) + ((v4.w + v5.w) + (v6.w + v7.w));
    }
    for (; i + 6 < e; i += 8) {
        int c0 = col[i], c1 = col[i + 2], c2 = col[i + 4], c3 = col[i + 6];
        float4 v0 = h4[c0 * 32 + li];
        float4 v1 = h4[c1 * 32 + li];
        float4 v2 = h4[c2 * 32 + li];
        float4 v3 = h4[c3 * 32 + li];
        ax += v0.x + v1.x + v2.x + v3.x;
        ay += v0.y + v1.y + v2.y + v3.y;
        az += v0.z + v1.z + v2.z + v3.z;
        aw += v0.w + v1.w + v2.w + v3.w;
    }
    for (; i < e; i += 2) {
        float4 v = h4[col[i] * 32 + li];
        ax += v.x; ay += v.y; az += v.z; aw += v.w;
    }
    ax += __shfl_xor(ax, 32, 64); ay += __shfl_xor(ay, 32, 64);
    az += __shfl_xor(az, 32, 64); aw += __shfl_xor(aw, 32, 64);
    if (lane < 32) {
        float4 o; o.x = ax; o.y = ay; o.z = az; o.w = aw;
        agg4[wv * 32 + li] = o;
    }
}

// ---------------- layer-2 matmul (64-node tile, Nn=8 -> 1.5 B LDS/FMA) + pooled partials ----------------
// 256 threads. LDS = WL 16 KB + aL 8.4 KB + gpart 2 KB = 26.6 KB -> 6 blocks/CU.
__global__ __launch_bounds__(256) void k_mm2p(const float* __restrict__ A, const float* __restrict__ W,
                                              const float* __restrict__ bias, const float* __restrict__ rsi,
                                              const int* __restrict__ gid, float* __restrict__ gsum,
                                              float* __restrict__ partials) {
    __shared__ float WL[32 * 128];
    __shared__ float aL[64][33];
    __shared__ float gpart[4][128];
    const int t = threadIdx.x;
    const int jq = t & 31;
    const int ns = t >> 5;
    const int n0 = blockIdx.x * 64;
    for (int u = t; u < 512; u += 256) ((float*)gpart)[u] = 0.f;
    float acc[8][4] = {};
    for (int kc = 0; kc < HID; kc += 32) {
        const float4* Wg = (const float4*)(W + kc * 128);
        float4* WL4 = (float4*)WL;
        __syncthreads();
#pragma unroll
        for (int u = 0; u < 4; ++u) WL4[t + 256 * u] = Wg[t + 256 * u];
        {
            int r = t >> 2, q = t & 3;
            int node = n0 + r;
#pragma unroll
            for (int h = 0; h < 2; ++h) {
                int qq = q + h * 4;
                float4 v = make_float4(0.f, 0.f, 0.f, 0.f);
                if (node < N_NODES) v = *(const float4*)(A + (size_t)node * HID + kc + qq * 4);
                aL[r][qq * 4 + 0] = v.x; aL[r][qq * 4 + 1] = v.y;
                aL[r][qq * 4 + 2] = v.z; aL[r][qq * 4 + 3] = v.w;
            }
        }
        __syncthreads();
#pragma unroll
        for (int k = 0; k < 32; ++k) {
            float4 wv = ((const float4*)WL)[k * 32 + jq];
#pragma unroll
            for (int i = 0; i < 8; ++i) {
                float av = aL[ns * 8 + i][k];
                acc[i][0] += av * wv.x; acc[i][1] += av * wv.y;
                acc[i][2] += av * wv.z; acc[i][3] += av * wv.w;
            }
        }
    }
    __syncthreads();
    // epilogue: relu + segment-sum by graph into gpart (LDS) / gsum (rare fallback)
    const int g0 = gid[n0];
    float4 bj = ((const float4*)bias)[jq];
    int curslot = -9;
    float p0 = 0.f, p1 = 0.f, p2 = 0.f, p3 = 0.f;
#pragma unroll
    for (int i = 0; i < 8; ++i) {
        int node = n0 + ns * 8 + i;
        if (node >= N_NODES) break;
        float ri = rsi[node];
        float ox = fmaxf(acc[i][0] * ri + bj.x, 0.f);
        float oy = fmaxf(acc[i][1] * ri + bj.y, 0.f);
        float oz = fmaxf(acc[i][2] * ri + bj.z, 0.f);
        float ow = fmaxf(acc[i][3] * ri + bj.w, 0.f);
        int slot = gid[node] - g0;
        if (slot != curslot) {
            if (curslot >= 0) {
                if (curslot < 4) {
                    atomicAdd(&gpart[curslot][jq * 4 + 0], p0);
                    atomicAdd(&gpart[curslot][jq * 4 + 1], p1);
                    atomicAdd(&gpart[curslot][jq * 4 + 2], p2);
                    atomicAdd(&gpart[curslot][jq * 4 + 3], p3);
                } else {
                    atomicAdd(&gsum[(g0 + curslot) * HID + jq * 4 + 0], p0);
                    atomicAdd(&gsum[(g0 + curslot) * HID + jq * 4 + 1], p1);
                    atomicAdd(&gsum[(g0 + curslot) * HID + jq * 4 + 2], p2);
                    atomicAdd(&gsum[(g0 + curslot) * HID + jq * 4 + 3], p3);
                }
            }
            curslot = slot; p0 = ox; p1 = oy; p2 = oz; p3 = ow;
        } else {
            p0 += ox; p1 += oy; p2 += oz; p3 += ow;
        }
    }
    if (curslot >= 0) {
        if (curslot < 4) {
            atomicAdd(&gpart[curslot][jq * 4 + 0], p0);
            atomicAdd(&gpart[curslot][jq * 4 + 1], p1);
            atomicAdd(&gpart[curslot][jq * 4 + 2], p2);
            atomicAdd(&gpart[curslot][jq * 4 + 3], p3);
        } else {
            atomicAdd(&gsum[(g0 + curslot) * HID + jq * 4 + 0], p0);
            atomicAdd(&gsum[(g0 + curslot) * HID + jq * 4 + 1], p1);
            atomicAdd(&gsum[(g0 + curslot) * HID + jq * 4 + 2], p2);
            atomicAdd(&gsum[(g0 + curslot) * HID + jq * 4 + 3], p3);
        }
    }
    __syncthreads();
    // stream ALL 4 slots (zeros included) as plain coalesced stores
    for (int u = t; u < 512; u += 256) partials[(size_t)blockIdx.x * 512 + u] = ((float*)gpart)[u];
}

// ---------------- pool reduction: gsum[g] = fallback + sum of covering block partials ----------------
__global__ __launch_bounds__(128) void k_pool(const float* __restrict__ partials, const int* __restrict__ gid,
                                              const int* __restrict__ gstart, float* __restrict__ gsum) {
    const int g = blockIdx.x, t = threadIdx.x;
    const int s = gstart[g], e = gstart[g + 1];
    float sum = gsum[g * HID + t];   // rare slot>=4 fallback contributions (gsum was memset to 0)
    if (e > s) {
        const int b0 = s >> 6, b1 = (e - 1) >> 6;
        for (int b = b0; b <= b1; ++b) {
            int sl = g - gid[b << 6];
            if (sl >= 0 && sl < 4) sum += partials[(size_t)b * 512 + sl * 128 + t];
        }
    }
    gsum[g * HID + t] = sum;
}

// ---------------- head: mean + 3-layer MLP per graph ----------------
__global__ __launch_bounds__(128) void k_head(const float* __restrict__ gsum, const int* __restrict__ gstart,
                                              const float* __restrict__ Wc1, const float* __restrict__ bc1,
                                              const float* __restrict__ Wc2, const float* __restrict__ bc2,
                                              const float* __restrict__ Wc3, const float* __restrict__ bc3,
                                              float* __restrict__ out) {
    int g = blockIdx.x, t = threadIdx.x;
    int s = gstart[g], e = gstart[g + 1];
    float cnt = fmaxf((float)(e - s), 1.0f);
    __shared__ float buf[HID];
    __shared__ float red[2];
    buf[t] = gsum[g * HID + t] / cnt;
    __syncthreads();
    float a = bc1[t];
#pragma unroll 8
    for (int k = 0; k < HID; ++k) a += buf[k] * Wc1[k * HID + t];
    a = fmaxf(a, 0.f);
    __syncthreads();
    buf[t] = a;
    __syncthreads();
    float b = bc2[t];
#pragma unroll 8
    for (int k = 0; k < HID; ++k) b += buf[k] * Wc2[k * HID + t];
    b = fmaxf(b, 0.f);
    float p = b * Wc3[t];
    for (int off = 32; off > 0; off >>= 1) p += __shfl_down(p, off, 64);
    if ((t & 63) == 0) red[t >> 6] = p;
    __syncthreads();
    if (t == 0) out[g] = red[0] + red[1] + bc3[0];
}

extern "C" void kernel_launch(void* const* d_in, const int* in_sizes, int n_in,
                              void* d_out, int out_size, void* d_ws, size_t ws_size,
                              hipStream_t stream) {
    const float* x   = (const float*)d_in[0];
    const int* esrc  = (const int*)d_in[1];
    const int* edst  = (const int*)d_in[2];
    const int* gid   = (const int*)d_in[3];
    const float* W1  = (const float*)d_in[4];
    const float* b1  = (const float*)d_in[5];
    const float* W2  = (const float*)d_in[6];
    const float* b2  = (const float*)d_in[7];
    const float* Wc1 = (const float*)d_in[8];
    const float* bc1 = (const float*)d_in[9];
    const float* Wc2 = (const float*)d_in[10];
    const float* bc2 = (const float*)d_in[11];
    const float* Wc3 = (const float*)d_in[12];
    const float* bc3 = (const float*)d_in[13];
    float* out = (float*)d_out;

    char* w = (char*)d_ws;
    size_t off = 0;
    auto alloc = [&](size_t bytes) -> char* {
        char* p = w + off;
        off += (bytes + 255) & ~(size_t)255;
        return p;
    };
    int* dcnt   = (int*)alloc((size_t)2 * (NBUCK + 1) * 4);  // dcnt+scnt contiguous (one memset)
    int* scnt   = dcnt + (NBUCK + 1);
    int* dbase  = (int*)alloc((size_t)(NBUCK + 1) * 4);
    int* sbase  = (int*)alloc((size_t)(NBUCK + 1) * 4);
    int* dcur   = (int*)alloc((size_t)NBUCK * 4);
    int* scur   = (int*)alloc((size_t)NBUCK * 4);
    float* rso  = (float*)alloc((size_t)N_NODES * 4);
    float* rsi  = (float*)alloc((size_t)N_NODES * 4);
    int* rowp   = (int*)alloc((size_t)(N_NODES + 1) * 4);
    int* gstart = (int*)alloc((size_t)(N_GRAPHS + 1) * 4);
    int* col    = (int*)alloc((size_t)N_EDGES * 4);
    float* gsum = (float*)alloc((size_t)N_GRAPHS * HID * 4);     // 256 KB
    float* partials = (float*)alloc((size_t)1563 * 512 * 4);     // 3.2 MB
    float* R1   = (float*)alloc((size_t)N_NODES * HID * 4);      // binnedD|binnedS, later agg2
    float* R2   = (float*)alloc((size_t)N_NODES * HID * 4);      // h1s
    int* binnedD = (int*)R1;                      // 6.4 MB (packed src|dstLocal)
    int* binnedS = (int*)R1 + (size_t)N_EDGES;    // 6.4 MB
    float* agg2 = R1;                             // 51.2 MB (binned dead after prep2)
    float* h1s  = R2;

    (void)in_sizes; (void)n_in; (void)out_size; (void)ws_size;

    hipMemsetAsync(dcnt, 0, (size_t)2 * (NBUCK + 1) * 4, stream);
    hipMemsetAsync(gsum, 0, (size_t)N_GRAPHS * HID * 4, stream);

    const int BB = (N_EDGES + 4095) / 4096;     // 391 edge blocks
    const int FB32 = N_NODES / 32;              // 3125 fused layer-1 blocks
    const int GB = (N_NODES * 64 + 255) / 256;  // one wave per node (gather)
    const int MB64 = (N_NODES + 63) / 64;       // 1563 layer-2 matmul blocks

    k_bhist<<<BB, 256, 0, stream>>>(esrc, edst, dcnt, scnt);
    k_bscan3<<<3, 512, 0, stream>>>(dcnt, scnt, gid, dbase, sbase, dcur, scur, gstart);
    k_bin2<<<BB, 256, 0, stream>>>(esrc, edst, dcur, scur, binnedD, binnedS);
    k_prep2<<<2 * NBUCK, 256, 0, stream>>>(dbase, sbase, binnedD, binnedS, rowp, rsi, rso, col);
    k_g64mm<<<FB32, 512, 0, stream>>>((const float4*)x, rso, rowp, col, W1, b1, rsi, h1s);
    k_gather128<<<GB, 256, 0, stream>>>((const float4*)h1s, rowp, col, (float4*)agg2);
    k_mm2p<<<MB64, 256, 0, stream>>>(agg2, W2, b2, rsi, gid, gsum, partials);
    k_pool<<<N_GRAPHS, 128, 0, stream>>>(partials, gid, gstart, gsum);
    k_head<<<N_GRAPHS, 128, 0, stream>>>(gsum, gstart, Wc1, bc1, Wc2, bc2, Wc3, bc3, out);
}

// Round 13
// 327.530 us; speedup vs baseline: 1.0666x; 1.0666x over previous
//
#include <hip/hip_runtime.h>

#define N_NODES 100000
#define N_EDGES 1600000
#define IN_DIM 64
#define HID 128
#define N_GRAPHS 512
#define NBUCK 391    // ceil(100000/256) buckets of 256 nodes

// ---------------- pass A: per-block LDS histogram of src/dst buckets ----------------
__global__ __launch_bounds__(256) void k_bhist(const int* __restrict__ src, const int* __restrict__ dst,
                                               int* __restrict__ dcnt, int* __restrict__ scnt) {
    __shared__ int hd[NBUCK];
    __shared__ int hs[NBUCK];
    const int t = threadIdx.x;
    const int e0 = blockIdx.x * 4096 + t * 16;
    for (int i = t; i < NBUCK; i += 256) { hd[i] = 0; hs[i] = 0; }
    __syncthreads();
    if (e0 < N_EDGES) {
        const int4* d4 = (const int4*)(dst + e0);
        const int4* s4 = (const int4*)(src + e0);
#pragma unroll
        for (int u = 0; u < 4; ++u) {
            int4 d = d4[u], s = s4[u];
            atomicAdd(&hd[d.x >> 8], 1); atomicAdd(&hd[d.y >> 8], 1);
            atomicAdd(&hd[d.z >> 8], 1); atomicAdd(&hd[d.w >> 8], 1);
            atomicAdd(&hs[s.x >> 8], 1); atomicAdd(&hs[s.y >> 8], 1);
            atomicAdd(&hs[s.z >> 8], 1); atomicAdd(&hs[s.w >> 8], 1);
        }
    }
    __syncthreads();
    for (int i = t; i < NBUCK; i += 256) {
        if (hd[i]) atomicAdd(&dcnt[i], hd[i]);
        if (hs[i]) atomicAdd(&scnt[i], hs[i]);
    }
}

// ---------------- scans (blocks 0,1) + per-graph bounds (block 2) ----------------
__global__ __launch_bounds__(512) void k_bscan3(const int* __restrict__ dcnt, const int* __restrict__ scnt,
                                                const int* __restrict__ gid,
                                                int* __restrict__ dbase, int* __restrict__ sbase,
                                                int* __restrict__ dcur, int* __restrict__ scur,
                                                int* __restrict__ gstart) {
    const int t = threadIdx.x;
    if (blockIdx.x == 2) {
        for (int g = t; g <= N_GRAPHS; g += 512) {
            int lo = 0, hi = N_NODES;
            while (lo < hi) {
                int mid = (lo + hi) >> 1;
                if (gid[mid] < g) lo = mid + 1; else hi = mid;
            }
            gstart[g] = lo;
        }
        return;
    }
    __shared__ int l[512];
    const int* cntp = (blockIdx.x == 0) ? dcnt : scnt;
    int* basep = (blockIdx.x == 0) ? dbase : sbase;
    int* curp  = (blockIdx.x == 0) ? dcur  : scur;
    int v = (t < NBUCK) ? cntp[t] : 0;
    l[t] = v;
    __syncthreads();
    for (int off = 1; off < 512; off <<= 1) {
        int x = (t >= off) ? l[t - off] : 0;
        __syncthreads();
        l[t] += x;
        __syncthreads();
    }
    if (t < NBUCK) {
        int excl = l[t] - v;
        basep[t] = excl; curp[t] = excl;
    }
    if (t == NBUCK - 1) basep[NBUCK] = l[t];
}

// ---------------- pass B: bin by dst bucket (packed src|dstLocal) AND by src bucket ----------------
__global__ __launch_bounds__(256) void k_bin2(const int* __restrict__ src, const int* __restrict__ dst,
                                              int* __restrict__ dcur, int* __restrict__ scur,
                                              int* __restrict__ binnedD, int* __restrict__ binnedS) {
    __shared__ int hd[NBUCK];
    __shared__ int bd[NBUCK];
    __shared__ int hs[NBUCK];
    __shared__ int bs[NBUCK];
    const int t = threadIdx.x;
    const int e0 = blockIdx.x * 4096 + t * 16;
    for (int i = t; i < NBUCK; i += 256) { hd[i] = 0; hs[i] = 0; }
    __syncthreads();
    if (e0 < N_EDGES) {
        const int4* d4 = (const int4*)(dst + e0);
        const int4* s4 = (const int4*)(src + e0);
#pragma unroll
        for (int u = 0; u < 4; ++u) {
            int4 d = d4[u], s = s4[u];
            atomicAdd(&hd[d.x >> 8], 1); atomicAdd(&hd[d.y >> 8], 1);
            atomicAdd(&hd[d.z >> 8], 1); atomicAdd(&hd[d.w >> 8], 1);
            atomicAdd(&hs[s.x >> 8], 1); atomicAdd(&hs[s.y >> 8], 1);
            atomicAdd(&hs[s.z >> 8], 1); atomicAdd(&hs[s.w >> 8], 1);
        }
    }
    __syncthreads();
    for (int i = t; i < NBUCK; i += 256) {
        int c = hd[i];
        bd[i] = c ? atomicAdd(&dcur[i], c) : 0;
        hd[i] = 0;
        c = hs[i];
        bs[i] = c ? atomicAdd(&scur[i], c) : 0;
        hs[i] = 0;
    }
    __syncthreads();
    if (e0 < N_EDGES) {
        const int4* d4 = (const int4*)(dst + e0);
        const int4* s4 = (const int4*)(src + e0);
#pragma unroll
        for (int u = 0; u < 4; ++u) {
            int4 d = d4[u];
            int4 s = s4[u];
            int bk, r;
            bk = d.x >> 8; r = atomicAdd(&hd[bk], 1); binnedD[bd[bk] + r] = s.x | ((d.x & 255) << 17);
            bk = d.y >> 8; r = atomicAdd(&hd[bk], 1); binnedD[bd[bk] + r] = s.y | ((d.y & 255) << 17);
            bk = d.z >> 8; r = atomicAdd(&hd[bk], 1); binnedD[bd[bk] + r] = s.z | ((d.z & 255) << 17);
            bk = d.w >> 8; r = atomicAdd(&hd[bk], 1); binnedD[bd[bk] + r] = s.w | ((d.w & 255) << 17);
            bk = s.x >> 8; r = atomicAdd(&hs[bk], 1); binnedS[bs[bk] + r] = s.x;
            bk = s.y >> 8; r = atomicAdd(&hs[bk], 1); binnedS[bs[bk] + r] = s.y;
            bk = s.z >> 8; r = atomicAdd(&hs[bk], 1); binnedS[bs[bk] + r] = s.z;
            bk = s.w >> 8; r = atomicAdd(&hs[bk], 1); binnedS[bs[bk] + r] = s.w;
        }
    }
}

// ---------------- pass C: CSR build (blocks 0..NBUCK-1) + out-degree rso (blocks NBUCK..) ----------------
__global__ __launch_bounds__(256) void k_prep2(const int* __restrict__ dbase, const int* __restrict__ sbase,
                                               const int* __restrict__ binnedD, const int* __restrict__ binnedS,
                                               int* __restrict__ rowp, float* __restrict__ rsi,
                                               float* __restrict__ rso, int* __restrict__ col) {
    const int t = threadIdx.x;
    if (blockIdx.x < NBUCK) {
        const int b = blockIdx.x;
        const int n0 = b * 256;
        __shared__ int cnt[256];
        __shared__ int scn[256];
        __shared__ int cur[256];
        __shared__ int sb[2];
        if (t < 2) sb[t] = dbase[b + t];
        cnt[t] = 0;
        __syncthreads();
        const int s = sb[0], e = sb[1];
        for (int i = s + t; i < e; i += 256) atomicAdd(&cnt[binnedD[i] >> 17], 1);
        __syncthreads();
        const int c = cnt[t];
        scn[t] = c;
        __syncthreads();
        for (int off = 1; off < 256; off <<= 1) {
            int v = (t >= off) ? scn[t - off] : 0;
            __syncthreads();
            scn[t] += v;
            __syncthreads();
        }
        const int excl = scn[t] - c;
        cur[t] = excl;
        if (n0 + t < N_NODES) {
            rowp[n0 + t] = s + excl;
            rsi[n0 + t] = 1.0f / sqrtf(fmaxf((float)c, 1.0f));
        }
        if (b == NBUCK - 1 && t == 0) rowp[N_NODES] = e;
        __syncthreads();
        for (int i = s + t; i < e; i += 256) {
            int p = binnedD[i];
            int r = atomicAdd(&cur[p >> 17], 1);
            col[s + r] = p & 0x1FFFF;
        }
    } else {
        const int b = blockIdx.x - NBUCK;
        const int n0 = b * 256;
        __shared__ int cnt2[256];
        __shared__ int sb2[2];
        if (t < 2) sb2[t] = sbase[b + t];
        cnt2[t] = 0;
        __syncthreads();
        const int s = sb2[0], e = sb2[1];
        for (int i = s + t; i < e; i += 256) atomicAdd(&cnt2[binnedS[i] - n0], 1);
        __syncthreads();
        if (n0 + t < N_NODES) rso[n0 + t] = 1.0f / sqrtf(fmaxf((float)cnt2[t], 1.0f));
    }
}

// ---------------- fused layer-1: gather(64) -> LDS -> matmul W1 (LDS-staged) -> h1s ----------------
__global__ __launch_bounds__(512, 8) void k_g64mm(const float4* __restrict__ x4, const float* __restrict__ rso,
                                                  const int* __restrict__ rowp, const int* __restrict__ col,
                                                  const float* __restrict__ W, const float* __restrict__ bias,
                                                  const float* __restrict__ rsi, float* __restrict__ out) {
    __shared__ float aggL[32][IN_DIM];   // 8 KB
    __shared__ float WL[32 * 128];       // 16 KB
    const int t = threadIdx.x;
    const int wid = t >> 6, lane = t & 63;
    const int n0 = blockIdx.x * 32;

    const int grp = lane >> 4, li = lane & 15;
#pragma unroll 1
    for (int it = 0; it < 4; ++it) {
        const int node = n0 + wid * 4 + it;
        const int s = rowp[node], e = rowp[node + 1];
        float ax = 0.f, ay = 0.f, az = 0.f, aw = 0.f;
        int i = s + grp;
        for (; i + 12 < e; i += 16) {
            int c0 = col[i], c1 = col[i + 4], c2 = col[i + 8], c3 = col[i + 12];
            float4 v0 = x4[c0 * 16 + li];
            float4 v1 = x4[c1 * 16 + li];
            float4 v2 = x4[c2 * 16 + li];
            float4 v3 = x4[c3 * 16 + li];
            float r0 = rso[c0], r1 = rso[c1], r2 = rso[c2], r3 = rso[c3];
            ax = fmaf(r0, v0.x, ax); ay = fmaf(r0, v0.y, ay); az = fmaf(r0, v0.z, az); aw = fmaf(r0, v0.w, aw);
            ax = fmaf(r1, v1.x, ax); ay = fmaf(r1, v1.y, ay); az = fmaf(r1, v1.z, az); aw = fmaf(r1, v1.w, aw);
            ax = fmaf(r2, v2.x, ax); ay = fmaf(r2, v2.y, ay); az = fmaf(r2, v2.z, az); aw = fmaf(r2, v2.w, aw);
            ax = fmaf(r3, v3.x, ax); ay = fmaf(r3, v3.y, ay); az = fmaf(r3, v3.z, az); aw = fmaf(r3, v3.w, aw);
        }
        for (; i + 4 < e; i += 8) {
            int c0 = col[i], c1 = col[i + 4];
            float4 v0 = x4[c0 * 16 + li];
            float4 v1 = x4[c1 * 16 + li];
            float r0 = rso[c0], r1 = rso[c1];
            ax = fmaf(r0, v0.x, ax); ay = fmaf(r0, v0.y, ay); az = fmaf(r0, v0.z, az); aw = fmaf(r0, v0.w, aw);
            ax = fmaf(r1, v1.x, ax); ay = fmaf(r1, v1.y, ay); az = fmaf(r1, v1.z, az); aw = fmaf(r1, v1.w, aw);
        }
        for (; i < e; i += 4) {
            int c = col[i];
            float4 v = x4[c * 16 + li];
            float r = rso[c];
            ax = fmaf(r, v.x, ax); ay = fmaf(r, v.y, ay); az = fmaf(r, v.z, az); aw = fmaf(r, v.w, aw);
        }
        ax += __shfl_xor(ax, 16, 64); ay += __shfl_xor(ay, 16, 64);
        az += __shfl_xor(az, 16, 64); aw += __shfl_xor(aw, 16, 64);
        ax += __shfl_xor(ax, 32, 64); ay += __shfl_xor(ay, 32, 64);
        az += __shfl_xor(az, 32, 64); aw += __shfl_xor(aw, 32, 64);
        if (lane < 16) {
            float4 o; o.x = ax; o.y = ay; o.z = az; o.w = aw;
            ((float4*)aggL[node - n0])[li] = o;
        }
    }

    const int jq = t & 31;
    const int ns = t >> 5;
    float acc[2][4] = {};
    for (int kc = 0; kc < IN_DIM; kc += 32) {
        const float4* Wg = (const float4*)(W + kc * 128);
        float4* WL4 = (float4*)WL;
        __syncthreads();
#pragma unroll
        for (int u = 0; u < 2; ++u) WL4[t + 512 * u] = Wg[t + 512 * u];
        __syncthreads();
#pragma unroll
        for (int k = 0; k < 32; ++k) {
            float4 wv = ((const float4*)WL)[k * 32 + jq];
            float a0 = aggL[ns * 2 + 0][kc + k];
            float a1 = aggL[ns * 2 + 1][kc + k];
            acc[0][0] += a0 * wv.x; acc[0][1] += a0 * wv.y; acc[0][2] += a0 * wv.z; acc[0][3] += a0 * wv.w;
            acc[1][0] += a1 * wv.x; acc[1][1] += a1 * wv.y; acc[1][2] += a1 * wv.z; acc[1][3] += a1 * wv.w;
        }
    }
    float4 bj = ((const float4*)bias)[jq];
#pragma unroll
    for (int i = 0; i < 2; ++i) {
        int node = n0 + ns * 2 + i;
        float ri = rsi[node];
        float ro = rso[node];
        float4 o;
        o.x = fmaxf(acc[i][0] * ri + bj.x, 0.f) * ro;
        o.y = fmaxf(acc[i][1] * ri + bj.y, 0.f) * ro;
        o.z = fmaxf(acc[i][2] * ri + bj.z, 0.f) * ro;
        o.w = fmaxf(acc[i][3] * ri + bj.w, 0.f) * ro;
        *(float4*)(out + (size_t)node * HID + jq * 4) = o;
    }
}

// ---------------- fused layer-2: gather(128) -> LDS -> matmul W2 (LDS-staged) -> per-block partials ----------------
// 512 threads = 32 dst nodes. LDS = agg 16 + WL 16 + gpart 2 = 34 KB -> 4 blocks/CU (thread cap).
__global__ __launch_bounds__(512, 8) void k_g128p(const float4* __restrict__ h4, const int* __restrict__ rowp,
                                                  const int* __restrict__ col, const float* __restrict__ W,
                                                  const float* __restrict__ bias, const float* __restrict__ rsi,
                                                  const int* __restrict__ gid, float* __restrict__ gsum,
                                                  float* __restrict__ partials) {
    __shared__ float agg[32][HID];   // 16 KB
    __shared__ float WL[32 * 128];   // 16 KB
    __shared__ float gpart[4][128];  // 2 KB
    const int t = threadIdx.x;
    const int wid = t >> 6, lane = t & 63;
    const int n0 = blockIdx.x * 32;
    if (t < 512) ((float*)gpart)[t] = 0.f;

    const int grp = lane >> 5, li = lane & 31;
#pragma unroll 1
    for (int it = 0; it < 4; ++it) {
        const int node = n0 + wid * 4 + it;
        const int s = rowp[node], e = rowp[node + 1];
        float ax = 0.f, ay = 0.f, az = 0.f, aw = 0.f;
        int i = s + grp;
        for (; i + 6 < e; i += 8) {
            int c0 = col[i], c1 = col[i + 2], c2 = col[i + 4], c3 = col[i + 6];
            float4 v0 = h4[c0 * 32 + li];
            float4 v1 = h4[c1 * 32 + li];
            float4 v2 = h4[c2 * 32 + li];
            float4 v3 = h4[c3 * 32 + li];
            ax += v0.x + v1.x + v2.x + v3.x;
            ay += v0.y + v1.y + v2.y + v3.y;
            az += v0.z + v1.z + v2.z + v3.z;
            aw += v0.w + v1.w + v2.w + v3.w;
        }
        for (; i < e; i += 2) {
            float4 v = h4[col[i] * 32 + li];
            ax += v.x; ay += v.y; az += v.z; aw += v.w;
        }
        ax += __shfl_xor(ax, 32, 64); ay += __shfl_xor(ay, 32, 64);
        az += __shfl_xor(az, 32, 64); aw += __shfl_xor(aw, 32, 64);
        if (lane < 32) {
            float4 o; o.x = ax; o.y = ay; o.z = az; o.w = aw;
            ((float4*)agg[node - n0])[li] = o;
        }
    }

    const int jq = t & 31;
    const int ns = t >> 5;
    float acc[2][4] = {};
    for (int kc = 0; kc < HID; kc += 32) {
        const float4* Wg = (const float4*)(W + kc * 128);
        float4* WL4 = (float4*)WL;
        __syncthreads();
#pragma unroll
        for (int u = 0; u < 2; ++u) WL4[t + 512 * u] = Wg[t + 512 * u];
        __syncthreads();
#pragma unroll
        for (int k = 0; k < 32; ++k) {
            float4 wv = ((const float4*)WL)[k * 32 + jq];
            float a0 = agg[ns * 2 + 0][kc + k];
            float a1 = agg[ns * 2 + 1][kc + k];
            acc[0][0] += a0 * wv.x; acc[0][1] += a0 * wv.y; acc[0][2] += a0 * wv.z; acc[0][3] += a0 * wv.w;
            acc[1][0] += a1 * wv.x; acc[1][1] += a1 * wv.y; acc[1][2] += a1 * wv.z; acc[1][3] += a1 * wv.w;
        }
    }

    // epilogue: relu + segment-sum by graph into gpart (LDS atomics); stream gpart to partials
    const int g0 = gid[n0];
    float4 bj = ((const float4*)bias)[jq];
    int curslot = -9;
    float p0 = 0.f, p1 = 0.f, p2 = 0.f, p3 = 0.f;
#pragma unroll
    for (int i = 0; i < 2; ++i) {
        int node = n0 + ns * 2 + i;
        float ri = rsi[node];
        float ox = fmaxf(acc[i][0] * ri + bj.x, 0.f);
        float oy = fmaxf(acc[i][1] * ri + bj.y, 0.f);
        float oz = fmaxf(acc[i][2] * ri + bj.z, 0.f);
        float ow = fmaxf(acc[i][3] * ri + bj.w, 0.f);
        int slot = gid[node] - g0;
        if (slot != curslot) {
            if (curslot >= 0) {
                if (curslot < 4) {
                    atomicAdd(&gpart[curslot][jq * 4 + 0], p0);
                    atomicAdd(&gpart[curslot][jq * 4 + 1], p1);
                    atomicAdd(&gpart[curslot][jq * 4 + 2], p2);
                    atomicAdd(&gpart[curslot][jq * 4 + 3], p3);
                } else {
                    atomicAdd(&gsum[(g0 + curslot) * HID + jq * 4 + 0], p0);
                    atomicAdd(&gsum[(g0 + curslot) * HID + jq * 4 + 1], p1);
                    atomicAdd(&gsum[(g0 + curslot) * HID + jq * 4 + 2], p2);
                    atomicAdd(&gsum[(g0 + curslot) * HID + jq * 4 + 3], p3);
                }
            }
            curslot = slot; p0 = ox; p1 = oy; p2 = oz; p3 = ow;
        } else {
            p0 += ox; p1 += oy; p2 += oz; p3 += ow;
        }
    }
    if (curslot >= 0) {
        if (curslot < 4) {
            atomicAdd(&gpart[curslot][jq * 4 + 0], p0);
            atomicAdd(&gpart[curslot][jq * 4 + 1], p1);
            atomicAdd(&gpart[curslot][jq * 4 + 2], p2);
            atomicAdd(&gpart[curslot][jq * 4 + 3], p3);
        } else {
            atomicAdd(&gsum[(g0 + curslot) * HID + jq * 4 + 0], p0);
            atomicAdd(&gsum[(g0 + curslot) * HID + jq * 4 + 1], p1);
            atomicAdd(&gsum[(g0 + curslot) * HID + jq * 4 + 2], p2);
            atomicAdd(&gsum[(g0 + curslot) * HID + jq * 4 + 3], p3);
        }
    }
    __syncthreads();
    // stream ALL 4 slots (zeros included -- workspace is poisoned) as plain stores
    if (t < 512) partials[(size_t)blockIdx.x * 512 + t] = ((float*)gpart)[t];
}

// ---------------- head: pool reduction (from partials) + mean + 3-layer MLP per graph ----------------
__global__ __launch_bounds__(128) void k_head(const float* __restrict__ partials, const int* __restrict__ gid,
                                              const float* __restrict__ gsum, const int* __restrict__ gstart,
                                              const float* __restrict__ Wc1, const float* __restrict__ bc1,
                                              const float* __restrict__ Wc2, const float* __restrict__ bc2,
                                              const float* __restrict__ Wc3, const float* __restrict__ bc3,
                                              float* __restrict__ out) {
    int g = blockIdx.x, t = threadIdx.x;
    int s = gstart[g], e = gstart[g + 1];
    float cnt = fmaxf((float)(e - s), 1.0f);
    // pool: rare slot>=4 fallback (gsum, memset to 0) + covering 32-node block partials
    float sum = gsum[g * HID + t];
    if (e > s) {
        const int b0 = s >> 5, b1 = (e - 1) >> 5;
        for (int b = b0; b <= b1; ++b) {
            int sl = g - gid[b << 5];
            if (sl >= 0 && sl < 4) sum += partials[(size_t)b * 512 + sl * 128 + t];
        }
    }
    __shared__ float buf[HID];
    __shared__ float red[2];
    buf[t] = sum / cnt;
    __syncthreads();
    float a = bc1[t];
#pragma unroll 8
    for (int k = 0; k < HID; ++k) a += buf[k] * Wc1[k * HID + t];
    a = fmaxf(a, 0.f);
    __syncthreads();
    buf[t] = a;
    __syncthreads();
    float b = bc2[t];
#pragma unroll 8
    for (int k = 0; k < HID; ++k) b += buf[k] * Wc2[k * HID + t];
    b = fmaxf(b, 0.f);
    float p = b * Wc3[t];
    for (int off = 32; off > 0; off >>= 1) p += __shfl_down(p, off, 64);
    if ((t & 63) == 0) red[t >> 6] = p;
    __syncthreads();
    if (t == 0) out[g] = red[0] + red[1] + bc3[0];
}

extern "C" void kernel_launch(void* const* d_in, const int* in_sizes, int n_in,
                              void* d_out, int out_size, void* d_ws, size_t ws_size,
                              hipStream_t stream) {
    const float* x   = (const float*)d_in[0];
    const int* esrc  = (const int*)d_in[1];
    const int* edst  = (const int*)d_in[2];
    const int* gid   = (const int*)d_in[3];
    const float* W1  = (const float*)d_in[4];
    const float* b1  = (const float*)d_in[5];
    const float* W2  = (const float*)d_in[6];
    const float* b2  = (const float*)d_in[7];
    const float* Wc1 = (const float*)d_in[8];
    const float* bc1 = (const float*)d_in[9];
    const float* Wc2 = (const float*)d_in[10];
    const float* bc2 = (const float*)d_in[11];
    const float* Wc3 = (const float*)d_in[12];
    const float* bc3 = (const float*)d_in[13];
    float* out = (float*)d_out;

    char* w = (char*)d_ws;
    size_t off = 0;
    auto alloc = [&](size_t bytes) -> char* {
        char* p = w + off;
        off += (bytes + 255) & ~(size_t)255;
        return p;
    };
    int* dcnt   = (int*)alloc((size_t)2 * (NBUCK + 1) * 4);  // dcnt+scnt contiguous (one memset)
    int* scnt   = dcnt + (NBUCK + 1);
    int* dbase  = (int*)alloc((size_t)(NBUCK + 1) * 4);
    int* sbase  = (int*)alloc((size_t)(NBUCK + 1) * 4);
    int* dcur   = (int*)alloc((size_t)NBUCK * 4);
    int* scur   = (int*)alloc((size_t)NBUCK * 4);
    float* rso  = (float*)alloc((size_t)N_NODES * 4);
    float* rsi  = (float*)alloc((size_t)N_NODES * 4);
    int* rowp   = (int*)alloc((size_t)(N_NODES + 1) * 4);
    int* gstart = (int*)alloc((size_t)(N_GRAPHS + 1) * 4);
    int* col    = (int*)alloc((size_t)N_EDGES * 4);
    float* gsum = (float*)alloc((size_t)N_GRAPHS * HID * 4);  // 256 KB
    float* R1   = (float*)alloc((size_t)N_NODES * HID * 4);   // binnedD|binnedS, later partials
    float* R2   = (float*)alloc((size_t)N_NODES * HID * 4);   // h1s
    int* binnedD = (int*)R1;                      // 6.4 MB (packed src|dstLocal)
    int* binnedS = (int*)R1 + (size_t)N_EDGES;    // 6.4 MB
    float* partials = R1;                         // 6.4 MB (dead binned space; 3125*4*128 floats)
    float* h1s  = R2;

    (void)in_sizes; (void)n_in; (void)out_size; (void)ws_size;

    hipMemsetAsync(dcnt, 0, (size_t)2 * (NBUCK + 1) * 4, stream);
    hipMemsetAsync(gsum, 0, (size_t)N_GRAPHS * HID * 4, stream);

    const int BB = (N_EDGES + 4095) / 4096;     // 391 edge blocks
    const int FB32 = N_NODES / 32;              // 3125 fused-layer blocks (exact: 100000 = 3125*32)

    k_bhist<<<BB, 256, 0, stream>>>(esrc, edst, dcnt, scnt);
    k_bscan3<<<3, 512, 0, stream>>>(dcnt, scnt, gid, dbase, sbase, dcur, scur, gstart);
    k_bin2<<<BB, 256, 0, stream>>>(esrc, edst, dcur, scur, binnedD, binnedS);
    k_prep2<<<2 * NBUCK, 256, 0, stream>>>(dbase, sbase, binnedD, binnedS, rowp, rsi, rso, col);
    k_g64mm<<<FB32, 512, 0, stream>>>((const float4*)x, rso, rowp, col, W1, b1, rsi, h1s);
    k_g128p<<<FB32, 512, 0, stream>>>((const float4*)h1s, rowp, col, W2, b2, rsi, gid, gsum, partials);
    k_head<<<N_GRAPHS, 128, 0, stream>>>(partials, gid, gsum, gstart, Wc1, bc1, Wc2, bc2, Wc3, bc3, out);
}